// Round 7
// baseline (176.790 us; speedup 1.0000x reference)
//
#include <hip/hip_runtime.h>
#include <hip/hip_bf16.h>

#define HH 512
#define WW 512
#define CIN 256
#define COUT 256
#define NPTS 65536
#define PW 514
#define NPIX (PW * PW)
#define NKT 72                      // K tiles of 32 (total K = 2304)

typedef __bf16 bf16x8 __attribute__((ext_vector_type(8)));
typedef float f32x16 __attribute__((ext_vector_type(16)));
typedef unsigned short us8 __attribute__((ext_vector_type(8)));

static __device__ __forceinline__ unsigned short f2bf(float f) {
  unsigned u = __builtin_bit_cast(unsigned, f);
  unsigned r = u + 0x7fffu + ((u >> 16) & 1u);
  return (unsigned short)(r >> 16);
}

static __device__ __forceinline__ void gload16(const void* g, void* l) {
  __builtin_amdgcn_global_load_lds(
      (const __attribute__((address_space(1))) unsigned int*)g,
      (__attribute__((address_space(3))) unsigned int*)l, 16, 0, 0);
}

// A layout (verified r2-r6): i = kt*8192 + o ; r = o>>5 (co),
// cp = (o>>3)&3, j = o&7, logical chunk c = cp ^ ((r>>1)&3),
// k = kt*32 + c*8 + j (k = t*256+ci). Linear 16KB DMA -> swizzled LDS tile.
__global__ __launch_bounds__(256) void prep_weight(const float* __restrict__ w,
                                                   unsigned short* __restrict__ A) {
  int i = blockIdx.x * 256 + threadIdx.x;       // 72*8192 = 589824 total
  int kt = i >> 13;
  int o  = i & 8191;
  int r  = o >> 5;
  int cp = (o >> 3) & 3;
  int j  = o & 7;
  int c  = cp ^ ((r >> 1) & 3);
  int k  = kt * 32 + c * 8 + j;
  int t  = k >> 8;
  int ci = k & 255;
  A[i] = f2bf(w[r * 2304 + ci * 9 + t]);
}

// Zero the border ring of the padded (514x514) bf16 feature image.
__global__ __launch_bounds__(256) void border_zero(unsigned short* __restrict__ Ft) {
  int g = blockIdx.x * 256 + threadIdx.x;
  if (g >= 2052 * 32) return;
  int p = g >> 5, c = g & 31;
  int py, px;
  if (p < 514)        { py = 0;        px = p; }
  else if (p < 1028)  { py = 513;      px = p - 514; }
  else if (p < 1540)  { py = p - 1027; px = 0; }
  else                { py = p - 1539; px = 513; }
  *(us8*)&Ft[((size_t)py * PW + px) * 256 + c * 8] = (us8){0, 0, 0, 0, 0, 0, 0, 0};
}

// Ft[((y+1)*514 + (x+1))*256 + ci] = bf16(feature[ci][y][x])
__global__ __launch_bounds__(256) void transpose_feat(const float* __restrict__ f,
                                                      unsigned short* __restrict__ Ft) {
  __shared__ unsigned short lds[64 * 264];
  int pix0 = blockIdx.x * 64;
  int y = pix0 >> 9, x0 = pix0 & 511;
  int tid = threadIdx.x;
  int p = tid & 63;
  int cb = tid >> 6;
  const float* src = f + pix0 + p;
  for (int c8 = 0; c8 < 8; ++c8) {
    us8 v;
#pragma unroll
    for (int j = 0; j < 8; ++j) {
      int ci = cb * 64 + c8 * 8 + j;
      v[j] = f2bf(src[ci * 262144]);
    }
    *(us8*)&lds[p * 264 + cb * 64 + c8 * 8] = v;
  }
  __syncthreads();
  int cic = tid & 31;
  int pr = tid >> 5;
  for (int g = 0; g < 8; ++g) {
    int p2 = pr + g * 8;
    us8 v = *(const us8*)&lds[p2 * 264 + cic * 8];
    *(us8*)&Ft[((size_t)((y + 1) * PW + x0 + 1 + p2)) * 256 + cic * 8] = v;
  }
}

// 256x256xK gather-GEMM. Deep decoupled streams: A 3 bufs staged t+2,
// B 6 bufs staged t+5 (5-tile latency budget). Uniform vmcnt(6)/tile:
// queue before HEAD(T) = [B(T),B(T+1),B(T+2),A(T),B(T+3),A(T+1),B(T+4)];
// drain-8 reaches exactly A(T). Tail stays uniform via clamped re-stages
// into dead buffers. 8 waves (2M x 4N), wave 128x64, 32x32 MFMA.
__global__ __launch_bounds__(512, 2) void gemm_gather(
    const unsigned short* __restrict__ A,     // prep'd, swizzle baked in
    const unsigned short* __restrict__ Ft,    // [514*514][256] bf16 padded
    const int* __restrict__ hidx,
    const int* __restrict__ widx,
    float* __restrict__ out) {
  __shared__ unsigned short lds[73728];       // A: 3*8192 @0, B: 6*8192 @24576
  unsigned short* ldsB = lds + 24576;

  int tid = threadIdx.x;
  int lane = tid & 63, wv = tid >> 6;
  int wm = wv & 1, wn = wv >> 1;
  int n0 = blockIdx.x << 8;

  // B gather: thread covers cols c = tid>>2 (pass0) and 128+c (pass1);
  // phys 16B chunk pc = tid&3 holds logical chunk lc = pc ^ ((c>>1)&3)
  // (note ((128+c)>>1)&3 == (c>>1)&3, so one key serves both passes).
  // 4 lanes per pixel read one contiguous 64B sector.
  int lcB = (tid & 3) ^ ((tid >> 3) & 3);
  const unsigned short* FtQ0;
  const unsigned short* FtQ1;
  {
    int cq = tid >> 2;
    FtQ0 = Ft + (long)(hidx[n0 + cq] * PW + widx[n0 + cq]) * 256 + lcB * 8;
    FtQ1 = Ft + (long)(hidx[n0 + 128 + cq] * PW + widx[n0 + 128 + cq]) * 256 + lcB * 8;
  }

#define STAGE_A(t_, ab_)                                                      \
  do {                                                                        \
    const unsigned short* g_ = A + (size_t)(t_) * 8192 + tid * 8;             \
    unsigned short* l_ = lds + (ab_) * 8192 + tid * 8;                        \
    gload16(g_, l_);                                                          \
    gload16(g_ + 4096, l_ + 4096);                                            \
  } while (0)

// Tile t_: tap = t_>>3, ci0 = (t_&7)*32. 2 gloads, 64B/pixel sectors.
#define STAGE_B(t_, bb_)                                                      \
  do {                                                                        \
    int tap_ = (t_) >> 3;                                                     \
    long off_ = (long)((tap_ / 3) * PW + (tap_ - (tap_ / 3) * 3)) * 256 +     \
                ((t_) & 7) * 32;                                              \
    unsigned short* l_ = ldsB + (bb_) * 8192 + tid * 8;                       \
    gload16(FtQ0 + off_, l_);                                                 \
    gload16(FtQ1 + off_, l_ + 4096);                                          \
  } while (0)

#define LDA(dst, ab_, kg_, mt_)                                               \
  do {                                                                        \
    int r_ = wm * 128 + (mt_) * 32 + (lane & 31);                             \
    int c_ = ((kg_) * 2 + (lane >> 5)) ^ ((r_ >> 1) & 3);                     \
    dst = *(const bf16x8*)&lds[(ab_) * 8192 + r_ * 32 + c_ * 8];              \
  } while (0)

#define LDB(dst, bb_, kg_, nt_)                                               \
  do {                                                                        \
    int col_ = wn * 64 + (nt_) * 32 + (lane & 31);                            \
    int pc_ = ((kg_) * 2 + (lane >> 5)) ^ ((col_ >> 1) & 3);                  \
    dst = *(const bf16x8*)&ldsB[(bb_) * 8192 + col_ * 32 + pc_ * 8];          \
  } while (0)

#define MFMA8(a0, a1, a2, a3, b0, b1)                                         \
  do {                                                                        \
    __builtin_amdgcn_s_setprio(1);                                            \
    acc[0][0] = __builtin_amdgcn_mfma_f32_32x32x16_bf16(a0, b0, acc[0][0], 0, 0, 0); \
    acc[0][1] = __builtin_amdgcn_mfma_f32_32x32x16_bf16(a0, b1, acc[0][1], 0, 0, 0); \
    acc[1][0] = __builtin_amdgcn_mfma_f32_32x32x16_bf16(a1, b0, acc[1][0], 0, 0, 0); \
    acc[1][1] = __builtin_amdgcn_mfma_f32_32x32x16_bf16(a1, b1, acc[1][1], 0, 0, 0); \
    acc[2][0] = __builtin_amdgcn_mfma_f32_32x32x16_bf16(a2, b0, acc[2][0], 0, 0, 0); \
    acc[2][1] = __builtin_amdgcn_mfma_f32_32x32x16_bf16(a2, b1, acc[2][1], 0, 0, 0); \
    acc[3][0] = __builtin_amdgcn_mfma_f32_32x32x16_bf16(a3, b0, acc[3][0], 0, 0, 0); \
    acc[3][1] = __builtin_amdgcn_mfma_f32_32x32x16_bf16(a3, b1, acc[3][1], 0, 0, 0); \
    __builtin_amdgcn_s_setprio(0);                                            \
  } while (0)

// Waits BEFORE barrier (r6 fix): cross-wave DMA residency after barrier.
#define HEAD()                                                                \
  do {                                                                        \
    asm volatile("s_waitcnt lgkmcnt(0)" ::: "memory");                        \
    asm volatile("s_waitcnt vmcnt(6)" ::: "memory");                          \
    __builtin_amdgcn_s_barrier();                                             \
    __builtin_amdgcn_sched_barrier(0);                                        \
  } while (0)

  f32x16 acc[4][2];
#pragma unroll
  for (int mt = 0; mt < 4; ++mt)
#pragma unroll
    for (int nt = 0; nt < 2; ++nt)
      acc[mt][nt] = (f32x16)(0.f);

  // Prologue in exact steady-queue order (14 loads):
  // B(0),B(1),B(2),A(0),B(3),A(1),B(4)
  STAGE_B(0, 0);
  STAGE_B(1, 1);
  STAGE_B(2, 2);
  STAGE_A(0, 0);
  STAGE_B(3, 3);
  STAGE_A(1, 1);
  STAGE_B(4, 4);

  for (int p = 0; p < 12; ++p) {
#pragma unroll
    for (int u = 0; u < 6; ++u) {
      int t = p * 6 + u;
      const int ab = u % 3;              // t%3 == u%3 (6 | outer stride)
      const int bb = u;                  // t%6 == u
      HEAD();
      bf16x8 xa0, xa1, xa2, xa3, xb0, xb1, ya0, ya1, ya2, ya3, yb0, yb1;
      LDA(xa0, ab, 0, 0); LDA(xa1, ab, 0, 1); LDA(xa2, ab, 0, 2);
      LDA(xa3, ab, 0, 3); LDB(xb0, bb, 0, 0); LDB(xb1, bb, 0, 1);
      // stage A(t+2) then B(t+5); clamped re-stages keep vmcnt uniform
      // and only ever overwrite buffers that are never read again.
      STAGE_A((t + 2 < NKT ? t + 2 : NKT - 1), (u + 2) % 3);
      STAGE_B((t + 5 < NKT ? t + 5 : NKT - 1), (u + 5) % 6);
      LDA(ya0, ab, 1, 0); LDA(ya1, ab, 1, 1); LDA(ya2, ab, 1, 2);
      LDA(ya3, ab, 1, 3); LDB(yb0, bb, 1, 0); LDB(yb1, bb, 1, 1);
      MFMA8(xa0, xa1, xa2, xa3, xb0, xb1);
      MFMA8(ya0, ya1, ya2, ya3, yb0, yb1);
    }
  }

#undef STAGE_A
#undef STAGE_B
#undef LDA
#undef LDB
#undef MFMA8
#undef HEAD

  // Epilogue (verified): col = lane&31, row = (r&3)+8*(r>>2)+4*(lane>>5)
  int colb = n0 + wn * 64 + (lane & 31);
  int rb = wm * 128 + ((lane >> 5) << 2);
#pragma unroll
  for (int mt = 0; mt < 4; ++mt)
#pragma unroll
    for (int nt = 0; nt < 2; ++nt)
#pragma unroll
      for (int r = 0; r < 16; ++r) {
        int row = rb + mt * 32 + (r & 3) + ((r >> 2) << 3);
        out[(size_t)row * NPTS + colb + nt * 32] = acc[mt][nt][r];
      }
}

// Safety-net path if workspace is too small: direct conv, fp32.
__global__ __launch_bounds__(256) void naive_conv(const float* __restrict__ f,
                                                  const float* __restrict__ w,
                                                  const int* __restrict__ hi,
                                                  const int* __restrict__ wi,
                                                  float* __restrict__ out) {
  int idx = blockIdx.x * 256 + threadIdx.x;
  int n = idx & (NPTS - 1);
  int co = idx >> 16;
  int bh = hi[n] - 1;
  int bw = wi[n] - 1;
  float acc = 0.f;
  for (int ci = 0; ci < CIN; ++ci) {
    const float* fc = f + (size_t)ci * 262144;
    const float* wc = w + (size_t)co * 2304 + ci * 9;
#pragma unroll
    for (int t = 0; t < 9; ++t) {
      int y = bh + t / 3, x = bw + t % 3;
      float v = (y >= 0 && y < 512 && x >= 0 && x < 512) ? fc[y * 512 + x] : 0.f;
      acc += wc[t] * v;
    }
  }
  out[(size_t)co * NPTS + n] = acc;
}

extern "C" void kernel_launch(void* const* d_in, const int* in_sizes, int n_in,
                              void* d_out, int out_size, void* d_ws, size_t ws_size,
                              hipStream_t stream) {
  const float* feature = (const float*)d_in[0];
  const float* weight  = (const float*)d_in[1];
  const int* hidx      = (const int*)d_in[2];
  const int* widx      = (const int*)d_in[3];
  float* out           = (float*)d_out;

  const size_t FT_OFF = 2ull * 1024 * 1024;
  const size_t FT_BYTES = (size_t)NPIX * 256 * 2;   // ~135 MiB
  const size_t NEED = FT_OFF + FT_BYTES;

  if (ws_size >= NEED) {
    unsigned short* Abf = (unsigned short*)d_ws;    // 1.125 MiB
    unsigned short* Ft = (unsigned short*)((char*)d_ws + FT_OFF);
    prep_weight<<<(NKT * 8192) / 256, 256, 0, stream>>>(weight, Abf);
    border_zero<<<(2052 * 32 + 255) / 256, 256, 0, stream>>>(Ft);
    transpose_feat<<<262144 / 64, 256, 0, stream>>>(feature, Ft);
    gemm_gather<<<NPTS / 256, 512, 0, stream>>>(Abf, Ft, hidx, widx, out);
  } else {
    naive_conv<<<(COUT * NPTS) / 256, 256, 0, stream>>>(feature, weight, hidx, widx, out);
  }
}

// Round 8
// 171.674 us; speedup vs baseline: 1.0298x; 1.0298x over previous
//
#include <hip/hip_runtime.h>
#include <hip/hip_bf16.h>

#define HH 512
#define WW 512
#define CIN 256
#define COUT 256
#define NPTS 65536
#define PW 514
#define NPIX (PW * PW)
#define NKT 72                      // K tiles of 32; 36 B pair-stages of 64 ci

typedef __bf16 bf16x8 __attribute__((ext_vector_type(8)));
typedef float f32x16 __attribute__((ext_vector_type(16)));
typedef unsigned short us8 __attribute__((ext_vector_type(8)));

static __device__ __forceinline__ unsigned short f2bf(float f) {
  unsigned u = __builtin_bit_cast(unsigned, f);
  unsigned r = u + 0x7fffu + ((u >> 16) & 1u);
  return (unsigned short)(r >> 16);
}

static __device__ __forceinline__ void gload16(const void* g, void* l) {
  __builtin_amdgcn_global_load_lds(
      (const __attribute__((address_space(1))) unsigned int*)g,
      (__attribute__((address_space(3))) unsigned int*)l, 16, 0, 0);
}

// A layout (verified r2-r7): i = kt*8192 + o ; r = o>>5 (co),
// cp = (o>>3)&3, j = o&7, logical chunk c = cp ^ ((r>>1)&3),
// k = kt*32 + c*8 + j (k = t*256+ci). Linear 16KB DMA -> swizzled LDS tile.
__global__ __launch_bounds__(256) void prep_weight(const float* __restrict__ w,
                                                   unsigned short* __restrict__ A) {
  int i = blockIdx.x * 256 + threadIdx.x;       // 72*8192 = 589824 total
  int kt = i >> 13;
  int o  = i & 8191;
  int r  = o >> 5;
  int cp = (o >> 3) & 3;
  int j  = o & 7;
  int c  = cp ^ ((r >> 1) & 3);
  int k  = kt * 32 + c * 8 + j;
  int t  = k >> 8;
  int ci = k & 255;
  A[i] = f2bf(w[r * 2304 + ci * 9 + t]);
}

// Zero the border ring of the padded (514x514) bf16 feature image.
__global__ __launch_bounds__(256) void border_zero(unsigned short* __restrict__ Ft) {
  int g = blockIdx.x * 256 + threadIdx.x;
  if (g >= 2052 * 32) return;
  int p = g >> 5, c = g & 31;
  int py, px;
  if (p < 514)        { py = 0;        px = p; }
  else if (p < 1028)  { py = 513;      px = p - 514; }
  else if (p < 1540)  { py = p - 1027; px = 0; }
  else                { py = p - 1539; px = 513; }
  *(us8*)&Ft[((size_t)py * PW + px) * 256 + c * 8] = (us8){0, 0, 0, 0, 0, 0, 0, 0};
}

// Ft[((y+1)*514 + (x+1))*256 + ci] = bf16(feature[ci][y][x])
__global__ __launch_bounds__(256) void transpose_feat(const float* __restrict__ f,
                                                      unsigned short* __restrict__ Ft) {
  __shared__ unsigned short lds[64 * 264];
  int pix0 = blockIdx.x * 64;
  int y = pix0 >> 9, x0 = pix0 & 511;
  int tid = threadIdx.x;
  int p = tid & 63;
  int cb = tid >> 6;
  const float* src = f + pix0 + p;
  for (int c8 = 0; c8 < 8; ++c8) {
    us8 v;
#pragma unroll
    for (int j = 0; j < 8; ++j) {
      int ci = cb * 64 + c8 * 8 + j;
      v[j] = f2bf(src[ci * 262144]);
    }
    *(us8*)&lds[p * 264 + cb * 64 + c8 * 8] = v;
  }
  __syncthreads();
  int cic = tid & 31;
  int pr = tid >> 5;
  for (int g = 0; g < 8; ++g) {
    int p2 = pr + g * 8;
    us8 v = *(const us8*)&lds[p2 * 264 + cic * 8];
    *(us8*)&Ft[((size_t)((y + 1) * PW + x0 + 1 + p2)) * 256 + cic * 8] = v;
  }
}

// 256x256xK gather-GEMM. B staged as 128B-per-pixel pair-granules (64 ci),
// halving gather transaction count vs 64B sectors. A x3 bufs staged t+2;
// B-pair x3 bufs staged q+2. Uniform vmcnt(6) at every HEAD (ledger
// hand-verified incl. clamped tail). 8 waves (2M x 4N), wave 128x64.
__global__ __launch_bounds__(512, 2) void gemm_gather(
    const unsigned short* __restrict__ A,     // prep'd, swizzle baked in
    const unsigned short* __restrict__ Ft,    // [514*514][256] bf16 padded
    const int* __restrict__ hidx,
    const int* __restrict__ widx,
    float* __restrict__ out) {
  __shared__ unsigned short lds[73728];       // A: 3*8192 @0, B: 3*16384 @24576
  unsigned short* ldsB = lds + 24576;

  int tid = threadIdx.x;
  int lane = tid & 63, wv = tid >> 6;
  int wm = wv & 1, wn = wv >> 1;
  int n0 = blockIdx.x << 8;

  // B gather: pass P covers cols [P*64, P*64+64). Thread handles pixel
  // col = P*64 + (tid>>3), physical 16B chunk pc = tid&7 holding logical
  // chunk lc = pc ^ (col&7) (col&7 == (tid>>3)&7 for all P). Each pixel's
  // 8 lanes read one contiguous 128B run (permuted internally).
  int pxc = tid >> 3;                  // 0..63
  int lcB = (tid & 7) ^ (pxc & 7);
  const unsigned short *FtP0, *FtP1, *FtP2, *FtP3;
  {
    FtP0 = Ft + (long)(hidx[n0 + pxc] * PW + widx[n0 + pxc]) * 256 + lcB * 8;
    FtP1 = Ft + (long)(hidx[n0 + 64 + pxc] * PW + widx[n0 + 64 + pxc]) * 256 + lcB * 8;
    FtP2 = Ft + (long)(hidx[n0 + 128 + pxc] * PW + widx[n0 + 128 + pxc]) * 256 + lcB * 8;
    FtP3 = Ft + (long)(hidx[n0 + 192 + pxc] * PW + widx[n0 + 192 + pxc]) * 256 + lcB * 8;
  }

#define STAGE_A(t_, ab_)                                                      \
  do {                                                                        \
    const unsigned short* g_ = A + (size_t)(t_) * 8192 + tid * 8;             \
    unsigned short* l_ = lds + (ab_) * 8192 + tid * 8;                        \
    gload16(g_, l_);                                                          \
    gload16(g_ + 4096, l_ + 4096);                                            \
  } while (0)

// Pair q_: tap = q_>>2, ci0 = (q_&3)*64. 4 gloads; 128B/pixel contiguous.
#define STAGE_BP(q_, bb_)                                                     \
  do {                                                                        \
    int tap_ = (q_) >> 2;                                                     \
    long off_ = (long)((tap_ / 3) * PW + (tap_ - (tap_ / 3) * 3)) * 256 +     \
                ((q_) & 3) * 64;                                              \
    unsigned short* l_ = ldsB + (bb_) * 16384 + tid * 8;                      \
    gload16(FtP0 + off_, l_);                                                 \
    gload16(FtP1 + off_, l_ + 4096);                                          \
    gload16(FtP2 + off_, l_ + 8192);                                          \
    gload16(FtP3 + off_, l_ + 12288);                                         \
  } while (0)

#define LDA(dst, ab_, kg_, mt_)                                               \
  do {                                                                        \
    int r_ = wm * 128 + (mt_) * 32 + (lane & 31);                             \
    int c_ = ((kg_) * 2 + (lane >> 5)) ^ ((r_ >> 1) & 3);                     \
    dst = *(const bf16x8*)&lds[(ab_) * 8192 + r_ * 32 + c_ * 8];              \
  } while (0)

// B LDS: [col][chunk]: offset = col*64 + phys*8; phys = logical ^ (col&7).
// Tile parity s_ selects logical chunks s_*4..s_*4+3.
#define LDB(dst, bb_, s_, kg_, nt_)                                           \
  do {                                                                        \
    int col_ = wn * 64 + (nt_) * 32 + (lane & 31);                            \
    int ph_ = ((s_) * 4 + (kg_) * 2 + (lane >> 5)) ^ (col_ & 7);              \
    dst = *(const bf16x8*)&ldsB[(bb_) * 16384 + col_ * 64 + ph_ * 8];         \
  } while (0)

#define MFMA8(a0, a1, a2, a3, b0, b1)                                         \
  do {                                                                        \
    __builtin_amdgcn_s_setprio(1);                                            \
    acc[0][0] = __builtin_amdgcn_mfma_f32_32x32x16_bf16(a0, b0, acc[0][0], 0, 0, 0); \
    acc[0][1] = __builtin_amdgcn_mfma_f32_32x32x16_bf16(a0, b1, acc[0][1], 0, 0, 0); \
    acc[1][0] = __builtin_amdgcn_mfma_f32_32x32x16_bf16(a1, b0, acc[1][0], 0, 0, 0); \
    acc[1][1] = __builtin_amdgcn_mfma_f32_32x32x16_bf16(a1, b1, acc[1][1], 0, 0, 0); \
    acc[2][0] = __builtin_amdgcn_mfma_f32_32x32x16_bf16(a2, b0, acc[2][0], 0, 0, 0); \
    acc[2][1] = __builtin_amdgcn_mfma_f32_32x32x16_bf16(a2, b1, acc[2][1], 0, 0, 0); \
    acc[3][0] = __builtin_amdgcn_mfma_f32_32x32x16_bf16(a3, b0, acc[3][0], 0, 0, 0); \
    acc[3][1] = __builtin_amdgcn_mfma_f32_32x32x16_bf16(a3, b1, acc[3][1], 0, 0, 0); \
    __builtin_amdgcn_s_setprio(0);                                            \
  } while (0)

// Waits BEFORE barrier (r6 rule): after the barrier, all waves' DMA slices
// through the drain point are LDS-resident.
#define HEAD()                                                                \
  do {                                                                        \
    asm volatile("s_waitcnt lgkmcnt(0)" ::: "memory");                        \
    asm volatile("s_waitcnt vmcnt(6)" ::: "memory");                          \
    __builtin_amdgcn_s_barrier();                                             \
    __builtin_amdgcn_sched_barrier(0);                                        \
  } while (0)

#define TILE(ab_, bb_, s_, ...)                                               \
  do {                                                                        \
    HEAD();                                                                   \
    bf16x8 xa0, xa1, xa2, xa3, xb0, xb1, ya0, ya1, ya2, ya3, yb0, yb1;        \
    LDA(xa0, ab_, 0, 0); LDA(xa1, ab_, 0, 1); LDA(xa2, ab_, 0, 2);            \
    LDA(xa3, ab_, 0, 3); LDB(xb0, bb_, s_, 0, 0); LDB(xb1, bb_, s_, 0, 1);    \
    __VA_ARGS__;                                                              \
    LDA(ya0, ab_, 1, 0); LDA(ya1, ab_, 1, 1); LDA(ya2, ab_, 1, 2);            \
    LDA(ya3, ab_, 1, 3); LDB(yb0, bb_, s_, 1, 0); LDB(yb1, bb_, s_, 1, 1);    \
    MFMA8(xa0, xa1, xa2, xa3, xb0, xb1);                                      \
    MFMA8(ya0, ya1, ya2, ya3, yb0, yb1);                                      \
  } while (0)

  f32x16 acc[4][2];
#pragma unroll
  for (int mt = 0; mt < 4; ++mt)
#pragma unroll
    for (int nt = 0; nt < 2; ++nt)
      acc[mt][nt] = (f32x16)(0.f);

  // Prologue in ledger order: BP(0), A(0), A(1), BP(1) -> 12 loads.
  STAGE_BP(0, 0);
  STAGE_A(0, 0);
  STAGE_A(1, 1);
  STAGE_BP(1, 1);

  // Steady state (hand-verified ledger): before every HEAD the outstanding
  // queue drains to exactly the 6 loads [A(next) + BP(next-pair)] with
  // vmcnt(6). Even tile t=2q stages A(t+2) then BP(q+2); odd stages A(t+3).
  // Tail clamps re-stage still-valid data into provably dead buffers.
  for (int P3 = 0; P3 < 12; ++P3) {
#pragma unroll
    for (int v = 0; v < 3; ++v) {
      int q = P3 * 3 + v;
      int t = 2 * q;
      TILE((2 * v) % 3, v, 0,
           STAGE_A((t + 2 < NKT ? t + 2 : NKT - 1), (2 * v + 2) % 3);
           STAGE_BP((q + 2 < 36 ? q + 2 : 35), (v + 2) % 3));
      TILE((2 * v + 1) % 3, v, 1,
           STAGE_A((t + 3 < NKT ? t + 3 : NKT - 1), (2 * v) % 3));
    }
  }

#undef STAGE_A
#undef STAGE_BP
#undef LDA
#undef LDB
#undef MFMA8
#undef HEAD
#undef TILE

  // Epilogue (verified): col = lane&31, row = (r&3)+8*(r>>2)+4*(lane>>5)
  int colb = n0 + wn * 64 + (lane & 31);
  int rb = wm * 128 + ((lane >> 5) << 2);
#pragma unroll
  for (int mt = 0; mt < 4; ++mt)
#pragma unroll
    for (int nt = 0; nt < 2; ++nt)
#pragma unroll
      for (int r = 0; r < 16; ++r) {
        int row = rb + mt * 32 + (r & 3) + ((r >> 2) << 3);
        out[(size_t)row * NPTS + colb + nt * 32] = acc[mt][nt][r];
      }
}

// Safety-net path if workspace is too small: direct conv, fp32.
__global__ __launch_bounds__(256) void naive_conv(const float* __restrict__ f,
                                                  const float* __restrict__ w,
                                                  const int* __restrict__ hi,
                                                  const int* __restrict__ wi,
                                                  float* __restrict__ out) {
  int idx = blockIdx.x * 256 + threadIdx.x;
  int n = idx & (NPTS - 1);
  int co = idx >> 16;
  int bh = hi[n] - 1;
  int bw = wi[n] - 1;
  float acc = 0.f;
  for (int ci = 0; ci < CIN; ++ci) {
    const float* fc = f + (size_t)ci * 262144;
    const float* wc = w + (size_t)co * 2304 + ci * 9;
#pragma unroll
    for (int t = 0; t < 9; ++t) {
      int y = bh + t / 3, x = bw + t % 3;
      float v = (y >= 0 && y < 512 && x >= 0 && x < 512) ? fc[y * 512 + x] : 0.f;
      acc += wc[t] * v;
    }
  }
  out[(size_t)co * NPTS + n] = acc;
}

extern "C" void kernel_launch(void* const* d_in, const int* in_sizes, int n_in,
                              void* d_out, int out_size, void* d_ws, size_t ws_size,
                              hipStream_t stream) {
  const float* feature = (const float*)d_in[0];
  const float* weight  = (const float*)d_in[1];
  const int* hidx      = (const int*)d_in[2];
  const int* widx      = (const int*)d_in[3];
  float* out           = (float*)d_out;

  const size_t FT_OFF = 2ull * 1024 * 1024;
  const size_t FT_BYTES = (size_t)NPIX * 256 * 2;   // ~135 MiB
  const size_t NEED = FT_OFF + FT_BYTES;

  if (ws_size >= NEED) {
    unsigned short* Abf = (unsigned short*)d_ws;    // 1.125 MiB
    unsigned short* Ft = (unsigned short*)((char*)d_ws + FT_OFF);
    prep_weight<<<(NKT * 8192) / 256, 256, 0, stream>>>(weight, Abf);
    border_zero<<<(2052 * 32 + 255) / 256, 256, 0, stream>>>(Ft);
    transpose_feat<<<262144 / 64, 256, 0, stream>>>(feature, Ft);
    gemm_gather<<<NPTS / 256, 512, 0, stream>>>(Abf, Ft, hidx, widx, out);
  } else {
    naive_conv<<<(COUT * NPTS) / 256, 256, 0, stream>>>(feature, weight, hidx, widx, out);
  }
}

// Round 9
// 159.590 us; speedup vs baseline: 1.1078x; 1.0757x over previous
//
#include <hip/hip_runtime.h>
#include <hip/hip_bf16.h>

#define HH 512
#define WW 512
#define CIN 256
#define COUT 256
#define NPTS 65536
#define PW 514
#define NPIX (PW * PW)
#define NKT 72                      // K tiles of 32; 36 B pair-stages of 64 ci

typedef __bf16 bf16x8 __attribute__((ext_vector_type(8)));
typedef float f32x16 __attribute__((ext_vector_type(16)));
typedef unsigned short us8 __attribute__((ext_vector_type(8)));

static __device__ __forceinline__ unsigned short f2bf(float f) {
  unsigned u = __builtin_bit_cast(unsigned, f);
  unsigned r = u + 0x7fffu + ((u >> 16) & 1u);
  return (unsigned short)(r >> 16);
}

static __device__ __forceinline__ void gload16(const void* g, void* l) {
  __builtin_amdgcn_global_load_lds(
      (const __attribute__((address_space(1))) unsigned int*)g,
      (__attribute__((address_space(3))) unsigned int*)l, 16, 0, 0);
}

// A layout (verified r2-r8): i = kt*8192 + o ; r = o>>5 (co),
// cp = (o>>3)&3, j = o&7, logical chunk c = cp ^ ((r>>1)&3),
// k = kt*32 + c*8 + j (k = t*256+ci). Linear 16KB DMA -> swizzled LDS tile.
__global__ __launch_bounds__(256) void prep_weight(const float* __restrict__ w,
                                                   unsigned short* __restrict__ A) {
  int i = blockIdx.x * 256 + threadIdx.x;       // 72*8192 = 589824 total
  int kt = i >> 13;
  int o  = i & 8191;
  int r  = o >> 5;
  int cp = (o >> 3) & 3;
  int j  = o & 7;
  int c  = cp ^ ((r >> 1) & 3);
  int k  = kt * 32 + c * 8 + j;
  int t  = k >> 8;
  int ci = k & 255;
  A[i] = f2bf(__builtin_nontemporal_load(&w[r * 2304 + ci * 9 + t]));
}

// Zero the border ring of the padded (514x514) bf16 feature image.
__global__ __launch_bounds__(256) void border_zero(unsigned short* __restrict__ Ft) {
  int g = blockIdx.x * 256 + threadIdx.x;
  if (g >= 2052 * 32) return;
  int p = g >> 5, c = g & 31;
  int py, px;
  if (p < 514)        { py = 0;        px = p; }
  else if (p < 1028)  { py = 513;      px = p - 514; }
  else if (p < 1540)  { py = p - 1027; px = 0; }
  else                { py = p - 1539; px = 513; }
  *(us8*)&Ft[((size_t)py * PW + px) * 256 + c * 8] = (us8){0, 0, 0, 0, 0, 0, 0, 0};
}

// Ft[((y+1)*514 + (x+1))*256 + ci] = bf16(feature[ci][y][x])
// f32 reads are NONTEMPORAL: 256 MB pure stream with zero reuse — keeping it
// out of L2/L3 preserves Ft residency for the gemm's random gathers.
__global__ __launch_bounds__(256) void transpose_feat(const float* __restrict__ f,
                                                      unsigned short* __restrict__ Ft) {
  __shared__ unsigned short lds[64 * 264];
  int pix0 = blockIdx.x * 64;
  int y = pix0 >> 9, x0 = pix0 & 511;
  int tid = threadIdx.x;
  int p = tid & 63;
  int cb = tid >> 6;
  const float* src = f + pix0 + p;
  for (int c8 = 0; c8 < 8; ++c8) {
    us8 v;
#pragma unroll
    for (int j = 0; j < 8; ++j) {
      int ci = cb * 64 + c8 * 8 + j;
      v[j] = f2bf(__builtin_nontemporal_load(&src[ci * 262144]));
    }
    *(us8*)&lds[p * 264 + cb * 64 + c8 * 8] = v;
  }
  __syncthreads();
  int cic = tid & 31;
  int pr = tid >> 5;
  for (int g = 0; g < 8; ++g) {
    int p2 = pr + g * 8;
    us8 v = *(const us8*)&lds[p2 * 264 + cic * 8];
    *(us8*)&Ft[((size_t)((y + 1) * PW + x0 + 1 + p2)) * 256 + cic * 8] = v;
  }
}

// 256x256xK gather-GEMM (structure identical to r8). Output stores are
// NONTEMPORAL (64 MB stream, zero reuse) to avoid evicting Ft from L3.
__global__ __launch_bounds__(512, 2) void gemm_gather(
    const unsigned short* __restrict__ A,     // prep'd, swizzle baked in
    const unsigned short* __restrict__ Ft,    // [514*514][256] bf16 padded
    const int* __restrict__ hidx,
    const int* __restrict__ widx,
    float* __restrict__ out) {
  __shared__ unsigned short lds[73728];       // A: 3*8192 @0, B: 3*16384 @24576
  unsigned short* ldsB = lds + 24576;

  int tid = threadIdx.x;
  int lane = tid & 63, wv = tid >> 6;
  int wm = wv & 1, wn = wv >> 1;
  int n0 = blockIdx.x << 8;

  // B gather: pass P covers cols [P*64, P*64+64). Thread handles pixel
  // col = P*64 + (tid>>3), physical 16B chunk pc = tid&7 holding logical
  // chunk lc = pc ^ (col&7). Each pixel's 8 lanes read one contiguous
  // 128B run (permuted internally).
  int pxc = tid >> 3;                  // 0..63
  int lcB = (tid & 7) ^ (pxc & 7);
  const unsigned short *FtP0, *FtP1, *FtP2, *FtP3;
  {
    FtP0 = Ft + (long)(hidx[n0 + pxc] * PW + widx[n0 + pxc]) * 256 + lcB * 8;
    FtP1 = Ft + (long)(hidx[n0 + 64 + pxc] * PW + widx[n0 + 64 + pxc]) * 256 + lcB * 8;
    FtP2 = Ft + (long)(hidx[n0 + 128 + pxc] * PW + widx[n0 + 128 + pxc]) * 256 + lcB * 8;
    FtP3 = Ft + (long)(hidx[n0 + 192 + pxc] * PW + widx[n0 + 192 + pxc]) * 256 + lcB * 8;
  }

#define STAGE_A(t_, ab_)                                                      \
  do {                                                                        \
    const unsigned short* g_ = A + (size_t)(t_) * 8192 + tid * 8;             \
    unsigned short* l_ = lds + (ab_) * 8192 + tid * 8;                        \
    gload16(g_, l_);                                                          \
    gload16(g_ + 4096, l_ + 4096);                                            \
  } while (0)

// Pair q_: tap = q_>>2, ci0 = (q_&3)*64. 4 gloads; 128B/pixel contiguous.
#define STAGE_BP(q_, bb_)                                                     \
  do {                                                                        \
    int tap_ = (q_) >> 2;                                                     \
    long off_ = (long)((tap_ / 3) * PW + (tap_ - (tap_ / 3) * 3)) * 256 +     \
                ((q_) & 3) * 64;                                              \
    unsigned short* l_ = ldsB + (bb_) * 16384 + tid * 8;                      \
    gload16(FtP0 + off_, l_);                                                 \
    gload16(FtP1 + off_, l_ + 4096);                                          \
    gload16(FtP2 + off_, l_ + 8192);                                          \
    gload16(FtP3 + off_, l_ + 12288);                                         \
  } while (0)

#define LDA(dst, ab_, kg_, mt_)                                               \
  do {                                                                        \
    int r_ = wm * 128 + (mt_) * 32 + (lane & 31);                             \
    int c_ = ((kg_) * 2 + (lane >> 5)) ^ ((r_ >> 1) & 3);                     \
    dst = *(const bf16x8*)&lds[(ab_) * 8192 + r_ * 32 + c_ * 8];              \
  } while (0)

// B LDS: [col][chunk]: offset = col*64 + phys*8; phys = logical ^ (col&7).
// Tile parity s_ selects logical chunks s_*4..s_*4+3.
#define LDB(dst, bb_, s_, kg_, nt_)                                           \
  do {                                                                        \
    int col_ = wn * 64 + (nt_) * 32 + (lane & 31);                            \
    int ph_ = ((s_) * 4 + (kg_) * 2 + (lane >> 5)) ^ (col_ & 7);              \
    dst = *(const bf16x8*)&ldsB[(bb_) * 16384 + col_ * 64 + ph_ * 8];         \
  } while (0)

#define MFMA8(a0, a1, a2, a3, b0, b1)                                         \
  do {                                                                        \
    __builtin_amdgcn_s_setprio(1);                                            \
    acc[0][0] = __builtin_amdgcn_mfma_f32_32x32x16_bf16(a0, b0, acc[0][0], 0, 0, 0); \
    acc[0][1] = __builtin_amdgcn_mfma_f32_32x32x16_bf16(a0, b1, acc[0][1], 0, 0, 0); \
    acc[1][0] = __builtin_amdgcn_mfma_f32_32x32x16_bf16(a1, b0, acc[1][0], 0, 0, 0); \
    acc[1][1] = __builtin_amdgcn_mfma_f32_32x32x16_bf16(a1, b1, acc[1][1], 0, 0, 0); \
    acc[2][0] = __builtin_amdgcn_mfma_f32_32x32x16_bf16(a2, b0, acc[2][0], 0, 0, 0); \
    acc[2][1] = __builtin_amdgcn_mfma_f32_32x32x16_bf16(a2, b1, acc[2][1], 0, 0, 0); \
    acc[3][0] = __builtin_amdgcn_mfma_f32_32x32x16_bf16(a3, b0, acc[3][0], 0, 0, 0); \
    acc[3][1] = __builtin_amdgcn_mfma_f32_32x32x16_bf16(a3, b1, acc[3][1], 0, 0, 0); \
    __builtin_amdgcn_s_setprio(0);                                            \
  } while (0)

// Waits BEFORE barrier (r6 rule): after the barrier, all waves' DMA slices
// through the drain point are LDS-resident.
#define HEAD()                                                                \
  do {                                                                        \
    asm volatile("s_waitcnt lgkmcnt(0)" ::: "memory");                        \
    asm volatile("s_waitcnt vmcnt(6)" ::: "memory");                          \
    __builtin_amdgcn_s_barrier();                                             \
    __builtin_amdgcn_sched_barrier(0);                                        \
  } while (0)

#define TILE(ab_, bb_, s_, ...)                                               \
  do {                                                                        \
    HEAD();                                                                   \
    bf16x8 xa0, xa1, xa2, xa3, xb0, xb1, ya0, ya1, ya2, ya3, yb0, yb1;        \
    LDA(xa0, ab_, 0, 0); LDA(xa1, ab_, 0, 1); LDA(xa2, ab_, 0, 2);            \
    LDA(xa3, ab_, 0, 3); LDB(xb0, bb_, s_, 0, 0); LDB(xb1, bb_, s_, 0, 1);    \
    __VA_ARGS__;                                                              \
    LDA(ya0, ab_, 1, 0); LDA(ya1, ab_, 1, 1); LDA(ya2, ab_, 1, 2);            \
    LDA(ya3, ab_, 1, 3); LDB(yb0, bb_, s_, 1, 0); LDB(yb1, bb_, s_, 1, 1);    \
    MFMA8(xa0, xa1, xa2, xa3, xb0, xb1);                                      \
    MFMA8(ya0, ya1, ya2, ya3, yb0, yb1);                                      \
  } while (0)

  f32x16 acc[4][2];
#pragma unroll
  for (int mt = 0; mt < 4; ++mt)
#pragma unroll
    for (int nt = 0; nt < 2; ++nt)
      acc[mt][nt] = (f32x16)(0.f);

  // Prologue in ledger order: BP(0), A(0), A(1), BP(1) -> 12 loads.
  STAGE_BP(0, 0);
  STAGE_A(0, 0);
  STAGE_A(1, 1);
  STAGE_BP(1, 1);

  // Steady state (ledger verified r8): uniform vmcnt(6) at every HEAD.
  for (int P3 = 0; P3 < 12; ++P3) {
#pragma unroll
    for (int v = 0; v < 3; ++v) {
      int q = P3 * 3 + v;
      int t = 2 * q;
      TILE((2 * v) % 3, v, 0,
           STAGE_A((t + 2 < NKT ? t + 2 : NKT - 1), (2 * v + 2) % 3);
           STAGE_BP((q + 2 < 36 ? q + 2 : 35), (v + 2) % 3));
      TILE((2 * v + 1) % 3, v, 1,
           STAGE_A((t + 3 < NKT ? t + 3 : NKT - 1), (2 * v) % 3));
    }
  }

#undef STAGE_A
#undef STAGE_BP
#undef LDA
#undef LDB
#undef MFMA8
#undef HEAD
#undef TILE

  // Epilogue (verified): col = lane&31, row = (r&3)+8*(r>>2)+4*(lane>>5).
  // Nontemporal stores: output is a pure stream, keep it out of L3.
  int colb = n0 + wn * 64 + (lane & 31);
  int rb = wm * 128 + ((lane >> 5) << 2);
#pragma unroll
  for (int mt = 0; mt < 4; ++mt)
#pragma unroll
    for (int nt = 0; nt < 2; ++nt)
#pragma unroll
      for (int r = 0; r < 16; ++r) {
        int row = rb + mt * 32 + (r & 3) + ((r >> 2) << 3);
        __builtin_nontemporal_store(acc[mt][nt][r],
                                    &out[(size_t)row * NPTS + colb + nt * 32]);
      }
}

// Safety-net path if workspace is too small: direct conv, fp32.
__global__ __launch_bounds__(256) void naive_conv(const float* __restrict__ f,
                                                  const float* __restrict__ w,
                                                  const int* __restrict__ hi,
                                                  const int* __restrict__ wi,
                                                  float* __restrict__ out) {
  int idx = blockIdx.x * 256 + threadIdx.x;
  int n = idx & (NPTS - 1);
  int co = idx >> 16;
  int bh = hi[n] - 1;
  int bw = wi[n] - 1;
  float acc = 0.f;
  for (int ci = 0; ci < CIN; ++ci) {
    const float* fc = f + (size_t)ci * 262144;
    const float* wc = w + (size_t)co * 2304 + ci * 9;
#pragma unroll
    for (int t = 0; t < 9; ++t) {
      int y = bh + t / 3, x = bw + t % 3;
      float v = (y >= 0 && y < 512 && x >= 0 && x < 512) ? fc[y * 512 + x] : 0.f;
      acc += wc[t] * v;
    }
  }
  out[(size_t)co * NPTS + n] = acc;
}

extern "C" void kernel_launch(void* const* d_in, const int* in_sizes, int n_in,
                              void* d_out, int out_size, void* d_ws, size_t ws_size,
                              hipStream_t stream) {
  const float* feature = (const float*)d_in[0];
  const float* weight  = (const float*)d_in[1];
  const int* hidx      = (const int*)d_in[2];
  const int* widx      = (const int*)d_in[3];
  float* out           = (float*)d_out;

  const size_t FT_OFF = 2ull * 1024 * 1024;
  const size_t FT_BYTES = (size_t)NPIX * 256 * 2;   // ~135 MiB
  const size_t NEED = FT_OFF + FT_BYTES;

  if (ws_size >= NEED) {
    unsigned short* Abf = (unsigned short*)d_ws;    // 1.125 MiB
    unsigned short* Ft = (unsigned short*)((char*)d_ws + FT_OFF);
    prep_weight<<<(NKT * 8192) / 256, 256, 0, stream>>>(weight, Abf);
    border_zero<<<(2052 * 32 + 255) / 256, 256, 0, stream>>>(Ft);
    transpose_feat<<<262144 / 64, 256, 0, stream>>>(feature, Ft);
    gemm_gather<<<NPTS / 256, 512, 0, stream>>>(Abf, Ft, hidx, widx, out);
  } else {
    naive_conv<<<(COUT * NPTS) / 256, 256, 0, stream>>>(feature, weight, hidx, widx, out);
  }
}